// Round 7
// baseline (29.257 us; speedup 1.0000x reference)
//
#include <hip/hip_runtime.h>

// Problem constants (from the reference file)
constexpr int kC = 3;
constexpr int kH = 2048;
constexpr int kW = 2048;
constexpr int kNB = 256;      // N_BOXES
constexpr int kHeight = 32;   // HEIGHT

typedef float f32x4 __attribute__((ext_vector_type(4)));

// Single kernel. Block = one (box, channel, 16-row half): writes a contiguous
// 16*max_w-float slab in sweep order (store-stream locality), gathers only its
// own channel plane (~26 KB footprint -> L1). Box math recomputed per block
// (proven neutral in R4/R5). Arithmetic bit-identical to the R6 fast path.
__global__ __launch_bounds__(256) void extract_kernel(
    const float* __restrict__ img,
    const float* __restrict__ boxes,
    const float* __restrict__ scale,
    float* __restrict__ out,
    int max_w, int nq, float inv_nq)
{
    // Bijective XCD swizzle: nwg = kNB*3*2 = 1536 = 8 * 192.
    const int bid = blockIdx.x;
    const int swz = (bid & 7) * 192 + (bid >> 3);
    const int rhalf = swz & 1;
    const int chb = swz >> 1;           // 0..767
    const int b = chb / 3;
    const int ch = chb - b * 3;

    // Per-box parameters (wave-uniform scalar math).
    const float s = scale[0];
    const float* bx = boxes + b * 8;
    const float p0x = bx[0] / s, p0y = bx[1] / s;
    const float p1x = bx[2] / s, p1y = bx[3] / s;
    const float p2x = bx[4] / s, p2y = bx[5] / s;
    const float p3x = bx[6] / s, p3y = bx[7] / s;

    const float hdx = p2x - p1x, hdy = p2y - p1y;
    const float h_dist = sqrtf(hdx * hdx + hdy * hdy);
    const float wdx = p1x - p0x, wdy = p1y - p0y;
    const float w_dist = sqrtf(wdx * wdx + wdy * wdy);
    const int width = (int)(32.0f * w_dist / fmaxf(h_dist, 1e-6f));
    const float curr_w = (float)width;
    const float inv_xden = 1.0f / fmaxf(curr_w - 1.0f, 1.0f);

    if (ch == 0 && rhalf == 0 && threadIdx.x == 0) {
        out[(size_t)kNB * kC * kHeight * max_w + b] = (float)(width / 8 * 8 + 8);
    }

    const float* plane = img + (size_t)ch * (kH * kW);
    // Strip start: rows [rhalf*16, rhalf*16+16) of (b, ch).
    float* dst = out + ((size_t)(b * kC + ch) * kHeight + rhalf * 16) * (size_t)max_w;

    constexpr float invW1 = 1.0f / 2047.0f;
    const int total = 16 * nq;

    for (int idx = threadIdx.x; idx < total; idx += 256) {
        // r16 = idx / nq via float reciprocal + exact correction (idx < 2^12ish)
        int r16 = (int)((float)idx * inv_nq);
        if (r16 * nq > idx) --r16;
        if ((r16 + 1) * nq <= idx) ++r16;
        const int qi = idx - r16 * nq;
        const int c0 = qi * 4;
        const int r = rhalf * 16 + r16;

        f32x4 o = {0.f, 0.f, 0.f, 0.f};

        if ((float)c0 < curr_w) {
            const float y = (float)r / 31.0f;
            const float omy = 1.0f - y;
#pragma unroll
            for (int j = 0; j < 4; ++j) {
                const float cf = (float)(c0 + j);
                if (cf < curr_w) {
                    const float x = cf * inv_xden;
                    const float omx = 1.0f - x;
                    const float w00 = omx * omy;
                    const float w10 = x * omy;
                    const float w11 = x * y;
                    const float w01 = omx * y;
                    const float res_x = ((w00 * p0x + w10 * p1x) + w11 * p2x) + w01 * p3x;
                    const float res_y = ((w00 * p0y + w10 * p1y) + w11 * p2y) + w01 * p3y;
                    const float grid_c = res_x * invW1 * 2.0f - 1.0f;
                    const float grid_r = res_y * invW1 * 2.0f - 1.0f;
                    const float fix = rintf((grid_c + 1.0f) * 2047.0f * 0.5f);
                    const float fiy = rintf((grid_r + 1.0f) * 2047.0f * 0.5f);
                    const bool inb = (fix >= 0.0f) && (fix <= 2047.0f) &&
                                     (fiy >= 0.0f) && (fiy <= 2047.0f);
                    const int ixc = (int)fminf(fmaxf(fix, 0.0f), 2047.0f);
                    const int iyc = (int)fminf(fmaxf(fiy, 0.0f), 2047.0f);
                    o[j] = inb ? plane[(size_t)iyc * kW + (size_t)ixc] : 0.0f;
                }
            }
        }

        *(f32x4*)(dst + (size_t)r16 * max_w + c0) = o;
    }
}

extern "C" void kernel_launch(void* const* d_in, const int* in_sizes, int n_in,
                              void* d_out, int out_size, void* d_ws, size_t ws_size,
                              hipStream_t stream) {
    const float* img   = (const float*)d_in[0];
    const float* boxes = (const float*)d_in[1];
    const float* scale = (const float*)d_in[2];
    float* out = (float*)d_out;

    // out_size = NB*C*HEIGHT*max_w + NB  ->  max_w recoverable (multiple of 8)
    const int max_w = (out_size - kNB) / (kNB * kC * kHeight);
    const int nq = max_w / 4;
    const float inv_nq = 1.0f / (float)nq;

    const int nblocks = kNB * kC * 2;   // 1536
    extract_kernel<<<nblocks, 256, 0, stream>>>(img, boxes, scale, out,
                                                max_w, nq, inv_nq);
}

// Round 8
// 24.788 us; speedup vs baseline: 1.1803x; 1.1803x over previous
//
#include <hip/hip_runtime.h>

// Problem constants (from the reference file)
constexpr int kC = 3;
constexpr int kH = 2048;
constexpr int kW = 2048;
constexpr int kNB = 256;      // N_BOXES
constexpr int kHeight = 32;   // HEIGHT

typedef float f32x4 __attribute__((ext_vector_type(4)));

// R3-champion kernel + XCD-aware box partitioning.
// Block = 64 threads = one 256-column chunk of one (box, row); 4 cols/thread.
// Linear grid with bijective XCD swizzle so XCD k owns boxes [32k, 32k+32):
// per-XCD img read footprint ~2.9 MB -> L2-resident across replays.
// Arithmetic is bit-identical to R3/R6 (fp contract off, precise divides).
__global__ __launch_bounds__(64) void extract_kernel(
    const float* __restrict__ img,
    const float* __restrict__ boxes,
    const float* __restrict__ scale,
    float* __restrict__ out,
    int max_w, int nqc, int blocksPerBox, int cpx)
{
#pragma clang fp contract(off)
    // Bijective XCD swizzle: nblocks = 8 * cpx.
    const int bid = blockIdx.x;
    const int swz = (bid & 7) * cpx + (bid >> 3);
    const int b  = swz / blocksPerBox;            // blocksPerBox = nqc*32
    const int rm = swz - b * blocksPerBox;
    const int r  = rm / nqc;
    const int qc = rm - r * nqc;

    const int c0 = (qc * 64 + threadIdx.x) * 4;
    if (c0 >= max_w) return;

    const float s = scale[0];
    const float* bx = boxes + b * 8;      // boxes[b, 4, 2]
    const float p0x = bx[0] / s, p0y = bx[1] / s;
    const float p1x = bx[2] / s, p1y = bx[3] / s;
    const float p2x = bx[4] / s, p2y = bx[5] / s;
    const float p3x = bx[6] / s, p3y = bx[7] / s;

    const float hdx = p2x - p1x, hdy = p2y - p1y;
    const float h_dist = sqrtf(hdx * hdx + hdy * hdy);
    const float wdx = p1x - p0x, wdy = p1y - p0y;
    const float w_dist = sqrtf(wdx * wdx + wdy * wdy);
    const int width = (int)(32.0f * w_dist / fmaxf(h_dist, 1e-6f));
    const float curr_w = (float)width;

    if (r == 0 && c0 == 0) {
        out[(size_t)kNB * kC * kHeight * max_w + b] = (float)(width / 8 * 8 + 8);
    }

    const size_t ch_stride = (size_t)kHeight * max_w;
    const size_t obase = (((size_t)b * kC) * (size_t)kHeight + (size_t)r) * (size_t)max_w + (size_t)c0;

    f32x4 o0 = {0.f, 0.f, 0.f, 0.f};
    f32x4 o1 = {0.f, 0.f, 0.f, 0.f};
    f32x4 o2 = {0.f, 0.f, 0.f, 0.f};

    if (c0 < width) {
        const float y = (float)r / 31.0f;
        const float omy = 1.0f - y;
        const float xden = fmaxf(curr_w - 1.0f, 1.0f);
#pragma unroll
        for (int j = 0; j < 4; ++j) {
            const float cf = (float)(c0 + j);
            if (cf < curr_w) {
                const float x = cf / xden;
                const float omx = 1.0f - x;
                const float w00 = omx * omy;
                const float w10 = x * omy;
                const float w11 = x * y;
                const float w01 = omx * y;
                const float res_x = w00 * p0x + w10 * p1x + w11 * p2x + w01 * p3x;
                const float res_y = w00 * p0y + w10 * p1y + w11 * p2y + w01 * p3y;

                const float grid_c = res_x / 2047.0f * 2.0f - 1.0f;
                const float grid_r = res_y / 2047.0f * 2.0f - 1.0f;
                const float fix = rintf((grid_c + 1.0f) * 2047.0f * 0.5f);
                const float fiy = rintf((grid_r + 1.0f) * 2047.0f * 0.5f);
                const bool inb = (fix >= 0.0f) && (fix <= 2047.0f) &&
                                 (fiy >= 0.0f) && (fiy <= 2047.0f);
                const int ixc = (int)fminf(fmaxf(fix, 0.0f), 2047.0f);
                const int iyc = (int)fminf(fmaxf(fiy, 0.0f), 2047.0f);

                const size_t ipix = (size_t)iyc * kW + (size_t)ixc;
                const float v0 = img[ipix];
                const float v1 = img[(size_t)kH * kW + ipix];
                const float v2 = img[2 * (size_t)kH * kW + ipix];
                o0[j] = inb ? v0 : 0.0f;
                o1[j] = inb ? v1 : 0.0f;
                o2[j] = inb ? v2 : 0.0f;
            }
        }
    }

    // 16B-aligned (max_w % 8 == 0, c0 % 4 == 0) streaming stores (R3 champion).
    __builtin_nontemporal_store(o0, (f32x4*)(out + obase));
    __builtin_nontemporal_store(o1, (f32x4*)(out + obase + ch_stride));
    __builtin_nontemporal_store(o2, (f32x4*)(out + obase + 2 * ch_stride));
}

extern "C" void kernel_launch(void* const* d_in, const int* in_sizes, int n_in,
                              void* d_out, int out_size, void* d_ws, size_t ws_size,
                              hipStream_t stream) {
    const float* img   = (const float*)d_in[0];
    const float* boxes = (const float*)d_in[1];
    const float* scale = (const float*)d_in[2];
    float* out = (float*)d_out;

    // out_size = NB*C*HEIGHT*max_w + NB  ->  max_w recoverable (multiple of 8)
    const int max_w = (out_size - kNB) / (kNB * kC * kHeight);
    const int quads = max_w / 4;
    const int nqc = (quads + 63) / 64;            // column chunks per row
    const int blocksPerBox = nqc * kHeight;       // 32 rows
    const int nblocks = blocksPerBox * kNB;       // kNB*32*nqc, divisible by 8
    const int cpx = nblocks / 8;

    extract_kernel<<<nblocks, 64, 0, stream>>>(img, boxes, scale, out,
                                               max_w, nqc, blocksPerBox, cpx);
}